// Round 1
// baseline (1875.182 us; speedup 1.0000x reference)
//
#include <hip/hip_runtime.h>
#include <math.h>

#define BN_EPS 1e-5f

__device__ __forceinline__ float gelu_exact(float x) {
    return 0.5f * x * (1.0f + erff(x * 0.7071067811865475f));
}

// out[n, j] = act( sum_k BN(concat(x1, x2*rowscale2)[n,k]) * W[k,j] + bias[j] )
// 64 rows per block, 256 threads. Each thread: 4 cols x RPT rows.
template<int K, int M, bool USE_BN, bool USE_GELU>
__global__ __launch_bounds__(256) void ffn_kernel(
    const float* __restrict__ x1, int K1,
    const float* __restrict__ x2,
    const float* __restrict__ rowscale2,
    const int* __restrict__ gidx,
    const float* __restrict__ gg, const float* __restrict__ bb,
    const float* __restrict__ mm, const float* __restrict__ vv,
    const float* __restrict__ W, const float* __restrict__ bias,
    float* __restrict__ out, int N)
{
    constexpr int LOGK = (K == 256) ? 8 : 7;
    __shared__ float xs[64 * K];
    const int tid = threadIdx.x;
    const int row0 = blockIdx.x * 64;
    const int K2 = K - K1;

    // stage 64 x K tile with BN applied
    for (int idx = tid; idx < 64 * K; idx += 256) {
        int r = idx >> LOGK;
        int c = idx & (K - 1);
        int row = row0 + r;
        float val = 0.0f;
        if (row < N) {
            int rs = gidx ? gidx[row] : row;
            if (c < K1) {
                val = x1[(size_t)rs * K1 + c];
            } else {
                val = x2[(size_t)rs * K2 + (c - K1)];
                if (rowscale2) val *= rowscale2[rs];
            }
            if (USE_BN)
                val = (val - mm[c]) * rsqrtf(vv[c] + BN_EPS) * gg[c] + bb[c];
        }
        xs[idx] = val;
    }
    __syncthreads();

    constexpr int CG  = M / 4;             // column groups of 4
    constexpr int RPT = (64 * CG) / 256;   // rows per thread
    const int cg = tid % CG;
    const int rg = tid / CG;
    const int j0 = cg * 4;
    const int r0 = rg * RPT;

    float acc[RPT][4];
    #pragma unroll
    for (int r = 0; r < RPT; ++r) {
        acc[r][0] = 0.0f; acc[r][1] = 0.0f; acc[r][2] = 0.0f; acc[r][3] = 0.0f;
    }

    #pragma unroll 4
    for (int k = 0; k < K; ++k) {
        const float4 w = *reinterpret_cast<const float4*>(W + (size_t)k * M + j0);
        #pragma unroll
        for (int r = 0; r < RPT; ++r) {
            float xv = xs[((r0 + r) << LOGK) + k];
            acc[r][0] = fmaf(xv, w.x, acc[r][0]);
            acc[r][1] = fmaf(xv, w.y, acc[r][1]);
            acc[r][2] = fmaf(xv, w.z, acc[r][2]);
            acc[r][3] = fmaf(xv, w.w, acc[r][3]);
        }
    }

    #pragma unroll
    for (int r = 0; r < RPT; ++r) {
        int row = row0 + r0 + r;
        if (row >= N) continue;
        float4 o;
        o.x = acc[r][0] + bias[j0 + 0];
        o.y = acc[r][1] + bias[j0 + 1];
        o.z = acc[r][2] + bias[j0 + 2];
        o.w = acc[r][3] + bias[j0 + 3];
        if (USE_GELU) {
            o.x = gelu_exact(o.x); o.y = gelu_exact(o.y);
            o.z = gelu_exact(o.z); o.w = gelu_exact(o.w);
        }
        *reinterpret_cast<float4*>(out + (size_t)row * M + j0) = o;
    }
}

__global__ __launch_bounds__(256) void count_kernel(
    const int* __restrict__ src, int* __restrict__ cnt, int E)
{
    int e = blockIdx.x * blockDim.x + threadIdx.x;
    if (e < E) atomicAdd(&cnt[src[e]], 1);
}

__global__ __launch_bounds__(256) void inv_kernel(
    const int* __restrict__ cnt, float* __restrict__ invc, int N)
{
    int n = blockIdx.x * blockDim.x + threadIdx.x;
    if (n < N) {
        int c = cnt[n];
        if (c < 1) c = 1;
        invc[n] = 1.0f / (float)c;
    }
}

// one wave per edge iteration: sum[src[e]] += y[dst[e]]  (128 floats = 2/lane)
__global__ __launch_bounds__(256) void scatter_kernel(
    const float* __restrict__ y,
    const int* __restrict__ src, const int* __restrict__ dst,
    float* __restrict__ sum, int E)
{
    const int lane = threadIdx.x & 63;
    const int wave = (blockIdx.x * blockDim.x + threadIdx.x) >> 6;
    const int nw = (gridDim.x * blockDim.x) >> 6;
    for (int e = wave; e < E; e += nw) {
        int s = src[e];
        int d = dst[e];
        const float2 val = *reinterpret_cast<const float2*>(y + (size_t)d * 128 + lane * 2);
        float* p = sum + (size_t)s * 128 + lane * 2;
        unsafeAtomicAdd(p,     val.x);
        unsafeAtomicAdd(p + 1, val.y);
    }
}

extern "C" void kernel_launch(void* const* d_in, const int* in_sizes, int n_in,
                              void* d_out, int out_size, void* d_ws, size_t ws_size,
                              hipStream_t stream) {
    const float* nf   = (const float*)d_in[0];
    const int*   esrc = (const int*)d_in[1];
    const int*   edst = (const int*)d_in[2];
    const int*   nidx = (const int*)d_in[3];
    auto in = [&](int i) { return (const float*)d_in[i]; };

    const int N = in_sizes[3];       // 50000
    const int E = in_sizes[1];       // 800000
    const int H = in_sizes[9];       // 128 (pre_bias)

    float* xA   = (float*)d_ws;
    float* xB   = xA + (size_t)N * H;
    float* y    = xB + (size_t)N * H;
    float* sum  = y  + (size_t)N * H;
    float* invc = sum + (size_t)N * H;
    int*   cnt  = (int*)(invc + N);

    const int ffnGrid = (N + 63) / 64;

    // degree counts (same for both convs)
    hipMemsetAsync(cnt, 0, (size_t)N * sizeof(int), stream);
    count_kernel<<<(E + 255) / 256, 256, 0, stream>>>(esrc, cnt, E);
    inv_kernel<<<(N + 255) / 256, 256, 0, stream>>>(cnt, invc, N);

    // pre FFN: [N,256] -> [N,128]
    ffn_kernel<256, 128, true, true><<<ffnGrid, 256, 0, stream>>>(
        nf, 256, nullptr, nullptr, nullptr,
        in(4), in(5), in(6), in(7), in(8), in(9), xA, N);

    // conv1: y = FFN_c1p(xA) on NODES (msg = y[dst])
    ffn_kernel<128, 128, true, true><<<ffnGrid, 256, 0, stream>>>(
        xA, 128, nullptr, nullptr, nullptr,
        in(10), in(11), in(12), in(13), in(14), in(15), y, N);
    hipMemsetAsync(sum, 0, (size_t)N * H * sizeof(float), stream);
    scatter_kernel<<<2048, 256, 0, stream>>>(y, esrc, edst, sum, E);
    ffn_kernel<256, 128, true, true><<<ffnGrid, 256, 0, stream>>>(
        xA, 128, sum, invc, nullptr,
        in(16), in(17), in(18), in(19), in(20), in(21), xB, N);

    // conv2
    ffn_kernel<128, 128, true, true><<<ffnGrid, 256, 0, stream>>>(
        xB, 128, nullptr, nullptr, nullptr,
        in(22), in(23), in(24), in(25), in(26), in(27), y, N);
    hipMemsetAsync(sum, 0, (size_t)N * H * sizeof(float), stream);
    scatter_kernel<<<2048, 256, 0, stream>>>(y, esrc, edst, sum, E);
    ffn_kernel<256, 128, true, true><<<ffnGrid, 256, 0, stream>>>(
        xB, 128, sum, invc, nullptr,
        in(28), in(29), in(30), in(31), in(32), in(33), xA, N);

    // post FFN
    ffn_kernel<128, 128, true, true><<<ffnGrid, 256, 0, stream>>>(
        xA, 128, nullptr, nullptr, nullptr,
        in(34), in(35), in(36), in(37), in(38), in(39), xB, N);

    // final linear with node_idx gather: out = xB[node_idx] @ out_W + out_b
    ffn_kernel<128, 32, false, false><<<ffnGrid, 256, 0, stream>>>(
        xB, 128, nullptr, nullptr, nidx,
        nullptr, nullptr, nullptr, nullptr, in(40), in(41), (float*)d_out, N);
}

// Round 2
// 690.825 us; speedup vs baseline: 2.7144x; 2.7144x over previous
//
#include <hip/hip_runtime.h>
#include <math.h>

#define BN_EPS 1e-5f

__device__ __forceinline__ float gelu_exact(float x) {
    return 0.5f * x * (1.0f + erff(x * 0.7071067811865475f));
}

// out[n, j] = act( sum_k BN(concat(x1, x2)[n,k]) * W[k,j] + bias[j] )
// 64 rows per block, 256 threads. Each thread: 4 cols x RPT rows.
template<int K, int M, bool USE_BN, bool USE_GELU>
__global__ __launch_bounds__(256) void ffn_kernel(
    const float* __restrict__ x1, int K1,
    const float* __restrict__ x2,
    const int* __restrict__ gidx,
    const float* __restrict__ gg, const float* __restrict__ bb,
    const float* __restrict__ mm, const float* __restrict__ vv,
    const float* __restrict__ W, const float* __restrict__ bias,
    float* __restrict__ out, int N)
{
    constexpr int LOGK = (K == 256) ? 8 : 7;
    __shared__ float xs[64 * K];
    const int tid = threadIdx.x;
    const int row0 = blockIdx.x * 64;
    const int K2 = K - K1;

    // stage 64 x K tile with BN applied
    for (int idx = tid; idx < 64 * K; idx += 256) {
        int r = idx >> LOGK;
        int c = idx & (K - 1);
        int row = row0 + r;
        float val = 0.0f;
        if (row < N) {
            int rs = gidx ? gidx[row] : row;
            if (c < K1) {
                val = x1[(size_t)rs * K1 + c];
            } else {
                val = x2[(size_t)rs * K2 + (c - K1)];
            }
            if (USE_BN)
                val = (val - mm[c]) * rsqrtf(vv[c] + BN_EPS) * gg[c] + bb[c];
        }
        xs[idx] = val;
    }
    __syncthreads();

    constexpr int CG  = M / 4;             // column groups of 4
    constexpr int RPT = (64 * CG) / 256;   // rows per thread
    const int cg = tid % CG;
    const int rg = tid / CG;
    const int j0 = cg * 4;
    const int r0 = rg * RPT;

    float acc[RPT][4];
    #pragma unroll
    for (int r = 0; r < RPT; ++r) {
        acc[r][0] = 0.0f; acc[r][1] = 0.0f; acc[r][2] = 0.0f; acc[r][3] = 0.0f;
    }

    #pragma unroll 4
    for (int k = 0; k < K; ++k) {
        const float4 w = *reinterpret_cast<const float4*>(W + (size_t)k * M + j0);
        #pragma unroll
        for (int r = 0; r < RPT; ++r) {
            float xv = xs[((r0 + r) << LOGK) + k];
            acc[r][0] = fmaf(xv, w.x, acc[r][0]);
            acc[r][1] = fmaf(xv, w.y, acc[r][1]);
            acc[r][2] = fmaf(xv, w.z, acc[r][2]);
            acc[r][3] = fmaf(xv, w.w, acc[r][3]);
        }
    }

    #pragma unroll
    for (int r = 0; r < RPT; ++r) {
        int row = row0 + r0 + r;
        if (row >= N) continue;
        float4 o;
        o.x = acc[r][0] + bias[j0 + 0];
        o.y = acc[r][1] + bias[j0 + 1];
        o.z = acc[r][2] + bias[j0 + 2];
        o.w = acc[r][3] + bias[j0 + 3];
        if (USE_GELU) {
            o.x = gelu_exact(o.x); o.y = gelu_exact(o.y);
            o.z = gelu_exact(o.z); o.w = gelu_exact(o.w);
        }
        *reinterpret_cast<float4*>(out + (size_t)row * M + j0) = o;
    }
}

__global__ __launch_bounds__(256) void count_kernel(
    const int* __restrict__ src, int* __restrict__ cnt, int E)
{
    int e = blockIdx.x * blockDim.x + threadIdx.x;
    if (e < E) atomicAdd(&cnt[src[e]], 1);
}

// exclusive scan step 1: per-block (256 elems) exclusive scan + block total
__global__ __launch_bounds__(256) void scan_blocks(
    const int* __restrict__ cnt, int* __restrict__ offs,
    int* __restrict__ partial, int N)
{
    __shared__ int sh[256];
    const int t = threadIdx.x;
    const int idx = blockIdx.x * 256 + t;
    int v = (idx < N) ? cnt[idx] : 0;
    sh[t] = v;
    __syncthreads();
    #pragma unroll
    for (int off = 1; off < 256; off <<= 1) {
        int x = (t >= off) ? sh[t - off] : 0;
        __syncthreads();
        sh[t] += x;
        __syncthreads();
    }
    if (idx < N) offs[idx] = sh[t] - v;       // exclusive within block
    if (t == 255) partial[blockIdx.x] = sh[255];
}

// step 2: exclusive scan of block totals (nb <= 256), single block
__global__ __launch_bounds__(256) void scan_partials(
    int* __restrict__ partial, int nb)
{
    __shared__ int sh[256];
    const int t = threadIdx.x;
    int v = (t < nb) ? partial[t] : 0;
    sh[t] = v;
    __syncthreads();
    #pragma unroll
    for (int off = 1; off < 256; off <<= 1) {
        int x = (t >= off) ? sh[t - off] : 0;
        __syncthreads();
        sh[t] += x;
        __syncthreads();
    }
    if (t < nb) partial[t] = sh[t] - v;       // exclusive
}

// step 3: add block offsets; set offs[N] = E
__global__ __launch_bounds__(256) void add_offsets(
    int* __restrict__ offs, const int* __restrict__ partial, int N, int E)
{
    const int idx = blockIdx.x * 256 + threadIdx.x;
    if (idx < N) offs[idx] += partial[idx >> 8];
    if (idx == N) offs[N] = E;
}

__global__ __launch_bounds__(256) void fill_csr(
    const int* __restrict__ src, const int* __restrict__ dst,
    const int* __restrict__ offs, int* __restrict__ cursor,
    int* __restrict__ csr_dst, int E)
{
    const int e = blockIdx.x * blockDim.x + threadIdx.x;
    if (e < E) {
        int s = src[e];
        int pos = offs[s] + atomicAdd(&cursor[s], 1);
        csr_dst[pos] = dst[e];
    }
}

// one wave per node: agg[n] = mean over CSR neighbors of y[d]  (128 f32, 2/lane)
__global__ __launch_bounds__(256) void aggregate_kernel(
    const float* __restrict__ y,
    const int* __restrict__ csr_dst, const int* __restrict__ offs,
    float* __restrict__ agg, int N)
{
    const int wave = (blockIdx.x * blockDim.x + threadIdx.x) >> 6;
    const int lane = threadIdx.x & 63;
    if (wave >= N) return;
    const int lo = offs[wave];
    const int hi = offs[wave + 1];
    float a0 = 0.0f, a1 = 0.0f;
    for (int base = lo; base < hi; base += 64) {
        int m = hi - base;
        if (m > 64) m = 64;
        int myd = (base + lane < hi) ? csr_dst[base + lane] : 0;
        #pragma unroll 4
        for (int i = 0; i < m; ++i) {
            int d = __shfl(myd, i);
            const float2 v = *reinterpret_cast<const float2*>(
                y + (size_t)d * 128 + lane * 2);
            a0 += v.x;
            a1 += v.y;
        }
    }
    const float inv = (hi > lo) ? 1.0f / (float)(hi - lo) : 0.0f;
    float2 o;
    o.x = a0 * inv;
    o.y = a1 * inv;
    *reinterpret_cast<float2*>(agg + (size_t)wave * 128 + lane * 2) = o;
}

extern "C" void kernel_launch(void* const* d_in, const int* in_sizes, int n_in,
                              void* d_out, int out_size, void* d_ws, size_t ws_size,
                              hipStream_t stream) {
    const float* nf   = (const float*)d_in[0];
    const int*   esrc = (const int*)d_in[1];
    const int*   edst = (const int*)d_in[2];
    const int*   nidx = (const int*)d_in[3];
    auto in = [&](int i) { return (const float*)d_in[i]; };

    const int N = in_sizes[3];       // 50000
    const int E = in_sizes[1];       // 800000
    const int H = 128;

    float* xA      = (float*)d_ws;
    float* xB      = xA + (size_t)N * H;
    float* y       = xB + (size_t)N * H;
    float* agg     = y  + (size_t)N * H;
    int*   cnt     = (int*)(agg + (size_t)N * H);
    int*   offs    = cnt + N;                 // N+1
    int*   cursor  = offs + (N + 1);
    int*   partial = cursor + N;              // 256
    int*   csr_dst = partial + 256;           // E

    const int ffnGrid = (N + 63) / 64;
    const int nb = (N + 255) / 256;

    // ---- CSR build (once, reused by both convs) ----
    hipMemsetAsync(cnt, 0, (size_t)N * sizeof(int), stream);
    hipMemsetAsync(cursor, 0, (size_t)N * sizeof(int), stream);
    count_kernel<<<(E + 255) / 256, 256, 0, stream>>>(esrc, cnt, E);
    scan_blocks<<<nb, 256, 0, stream>>>(cnt, offs, partial, N);
    scan_partials<<<1, 256, 0, stream>>>(partial, nb);
    add_offsets<<<(N + 256) / 256, 256, 0, stream>>>(offs, partial, N, E);
    fill_csr<<<(E + 255) / 256, 256, 0, stream>>>(esrc, edst, offs, cursor, csr_dst, E);

    // ---- pre FFN: [N,256] -> [N,128] ----
    ffn_kernel<256, 128, true, true><<<ffnGrid, 256, 0, stream>>>(
        nf, 256, nullptr, nullptr,
        in(4), in(5), in(6), in(7), in(8), in(9), xA, N);

    // ---- conv1 ----
    ffn_kernel<128, 128, true, true><<<ffnGrid, 256, 0, stream>>>(
        xA, 128, nullptr, nullptr,
        in(10), in(11), in(12), in(13), in(14), in(15), y, N);
    aggregate_kernel<<<(N * 64 + 255) / 256, 256, 0, stream>>>(y, csr_dst, offs, agg, N);
    ffn_kernel<256, 128, true, true><<<ffnGrid, 256, 0, stream>>>(
        xA, 128, agg, nullptr,
        in(16), in(17), in(18), in(19), in(20), in(21), xB, N);

    // ---- conv2 ----
    ffn_kernel<128, 128, true, true><<<ffnGrid, 256, 0, stream>>>(
        xB, 128, nullptr, nullptr,
        in(22), in(23), in(24), in(25), in(26), in(27), y, N);
    aggregate_kernel<<<(N * 64 + 255) / 256, 256, 0, stream>>>(y, csr_dst, offs, agg, N);
    ffn_kernel<256, 128, true, true><<<ffnGrid, 256, 0, stream>>>(
        xB, 128, agg, nullptr,
        in(28), in(29), in(30), in(31), in(32), in(33), xA, N);

    // ---- post FFN ----
    ffn_kernel<128, 128, true, true><<<ffnGrid, 256, 0, stream>>>(
        xA, 128, nullptr, nullptr,
        in(34), in(35), in(36), in(37), in(38), in(39), xB, N);

    // ---- final linear with node_idx gather ----
    ffn_kernel<128, 32, false, false><<<ffnGrid, 256, 0, stream>>>(
        xB, 128, nullptr, nidx,
        nullptr, nullptr, nullptr, nullptr, in(40), in(41), (float*)d_out, N);
}

// Round 3
// 391.307 us; speedup vs baseline: 4.7921x; 1.7654x over previous
//
#include <hip/hip_runtime.h>
#include <math.h>

#define BN_EPS 1e-5f

typedef _Float16 f16x8 __attribute__((ext_vector_type(8)));
typedef float f32x4 __attribute__((ext_vector_type(4)));

__device__ __forceinline__ float gelu_exact(float x) {
    return 0.5f * x * (1.0f + erff(x * 0.7071067811865475f));
}

// ---------------- fp32 vector FFN (kept for the small final linear) ----------
template<int K, int M, bool USE_BN, bool USE_GELU>
__global__ __launch_bounds__(256) void ffn_kernel(
    const float* __restrict__ x1, int K1,
    const float* __restrict__ x2,
    const int* __restrict__ gidx,
    const float* __restrict__ gg, const float* __restrict__ bb,
    const float* __restrict__ mm, const float* __restrict__ vv,
    const float* __restrict__ W, const float* __restrict__ bias,
    float* __restrict__ out, int N)
{
    constexpr int LOGK = (K == 256) ? 8 : 7;
    __shared__ float xs[64 * K];
    const int tid = threadIdx.x;
    const int row0 = blockIdx.x * 64;
    const int K2 = K - K1;

    for (int idx = tid; idx < 64 * K; idx += 256) {
        int r = idx >> LOGK;
        int c = idx & (K - 1);
        int row = row0 + r;
        float val = 0.0f;
        if (row < N) {
            int rs = gidx ? gidx[row] : row;
            if (c < K1) val = x1[(size_t)rs * K1 + c];
            else        val = x2[(size_t)rs * K2 + (c - K1)];
            if (USE_BN)
                val = (val - mm[c]) * rsqrtf(vv[c] + BN_EPS) * gg[c] + bb[c];
        }
        xs[idx] = val;
    }
    __syncthreads();

    constexpr int CG  = M / 4;
    constexpr int RPT = (64 * CG) / 256;
    const int cg = tid % CG;
    const int rg = tid / CG;
    const int j0 = cg * 4;
    const int r0 = rg * RPT;

    float acc[RPT][4];
    #pragma unroll
    for (int r = 0; r < RPT; ++r)
        { acc[r][0]=0; acc[r][1]=0; acc[r][2]=0; acc[r][3]=0; }

    #pragma unroll 4
    for (int k = 0; k < K; ++k) {
        const float4 w = *reinterpret_cast<const float4*>(W + (size_t)k * M + j0);
        #pragma unroll
        for (int r = 0; r < RPT; ++r) {
            float xv = xs[((r0 + r) << LOGK) + k];
            acc[r][0] = fmaf(xv, w.x, acc[r][0]);
            acc[r][1] = fmaf(xv, w.y, acc[r][1]);
            acc[r][2] = fmaf(xv, w.z, acc[r][2]);
            acc[r][3] = fmaf(xv, w.w, acc[r][3]);
        }
    }

    #pragma unroll
    for (int r = 0; r < RPT; ++r) {
        int row = row0 + r0 + r;
        if (row >= N) continue;
        float4 o;
        o.x = acc[r][0] + bias[j0 + 0];
        o.y = acc[r][1] + bias[j0 + 1];
        o.z = acc[r][2] + bias[j0 + 2];
        o.w = acc[r][3] + bias[j0 + 3];
        if (USE_GELU) {
            o.x = gelu_exact(o.x); o.y = gelu_exact(o.y);
            o.z = gelu_exact(o.z); o.w = gelu_exact(o.w);
        }
        *reinterpret_cast<float4*>(out + (size_t)row * M + j0) = o;
    }
}

// ---------------- BN-fold weight prep: WT[j][k] = rs*g*W[k][j] (fp16),
// bias_out[j] = bias[j] + sum_k (b[k]-m[k]*rs*g)*W[k][j] -------------------
template<int K, int M>
__global__ __launch_bounds__(256) void prep_w(
    const float* __restrict__ gg, const float* __restrict__ bb,
    const float* __restrict__ mm, const float* __restrict__ vv,
    const float* __restrict__ W, const float* __restrict__ bias,
    _Float16* __restrict__ WT, float* __restrict__ bias_out)
{
    const int j = blockIdx.x;
    const int t = threadIdx.x;
    __shared__ float red[256];
    float acc = 0.0f;
    for (int k = t; k < K; k += 256) {
        float rs = rsqrtf(vv[k] + BN_EPS) * gg[k];
        float w  = W[(size_t)k * M + j];
        WT[(size_t)j * K + k] = (_Float16)(rs * w);
        acc += (bb[k] - mm[k] * rs) * w;
    }
    red[t] = acc;
    __syncthreads();
    #pragma unroll
    for (int s = 128; s > 0; s >>= 1) {
        if (t < s) red[t] += red[t + s];
        __syncthreads();
    }
    if (t == 0) bias_out[j] = bias[j] + red[0];
}

// ---------------- MFMA FFN: out[64 x 128] per block, fp16 in / fp32 out -----
// x staged in LDS fp16 with XOR swizzle; WT [128][K] fp16 L2-resident.
template<int K>
__global__ __launch_bounds__(256) void ffn_mfma(
    const float* __restrict__ x1, int K1,
    const float* __restrict__ x2,
    const _Float16* __restrict__ WT,
    const float* __restrict__ bias,
    float* __restrict__ out, int N)
{
    constexpr int M  = 128;
    constexpr int KB = K * 2;          // row bytes in LDS
    constexpr int CPR = K / 8;         // 8-elem chunks per row
    constexpr int NKK = K / 32;        // K-steps
    __shared__ __align__(16) char xs[64 * KB];

    const int tid  = threadIdx.x;
    const int row0 = blockIdx.x * 64;

    // stage 64 x K fp32 -> fp16, swizzled
    for (int c = tid; c < 64 * CPR; c += 256) {
        int r  = c / CPR;
        int kc = c % CPR;
        int k0 = kc * 8;
        int row = row0 + r;
        f16x8 h;
        #pragma unroll
        for (int i = 0; i < 8; ++i) h[i] = (_Float16)0.0f;
        if (row < N) {
            const float* src; int kk, stride;
            if (k0 < K1) { src = x1; kk = k0;      stride = K1; }
            else         { src = x2; kk = k0 - K1; stride = K - K1; }
            const float* p = src + (size_t)row * stride + kk;
            const float4 a = *reinterpret_cast<const float4*>(p);
            const float4 b = *reinterpret_cast<const float4*>(p + 4);
            h[0]=(_Float16)a.x; h[1]=(_Float16)a.y; h[2]=(_Float16)a.z; h[3]=(_Float16)a.w;
            h[4]=(_Float16)b.x; h[5]=(_Float16)b.y; h[6]=(_Float16)b.z; h[7]=(_Float16)b.w;
        }
        int byte = r * KB + ((k0 * 2) ^ ((r & 7) << 4));
        *reinterpret_cast<f16x8*>(&xs[byte]) = h;
    }
    __syncthreads();

    const int wave = tid >> 6;
    const int lane = tid & 63;
    const int lrow = lane & 15;
    const int lj   = lane >> 4;
    const int lk   = lj * 8;
    const int colbase = wave * 32;

    // preload B fragments (W' cols), 16B each, L2-resident
    f16x8 bfrag[2][NKK];
    #pragma unroll
    for (int n = 0; n < 2; ++n) {
        int col = colbase + n * 16 + lrow;
        #pragma unroll
        for (int kk = 0; kk < NKK; ++kk)
            bfrag[n][kk] = *reinterpret_cast<const f16x8*>(
                WT + (size_t)col * K + kk * 32 + lk);
    }

    f32x4 acc[4][2];
    #pragma unroll
    for (int m = 0; m < 4; ++m)
        #pragma unroll
        for (int n = 0; n < 2; ++n)
            acc[m][n] = (f32x4){0.f, 0.f, 0.f, 0.f};

    #pragma unroll
    for (int kk = 0; kk < NKK; ++kk) {
        #pragma unroll
        for (int m = 0; m < 4; ++m) {
            int r  = m * 16 + lrow;
            int k0 = kk * 32 + lk;
            f16x8 a = *reinterpret_cast<const f16x8*>(
                &xs[r * KB + ((k0 * 2) ^ ((r & 7) << 4))]);
            acc[m][0] = __builtin_amdgcn_mfma_f32_16x16x32_f16(a, bfrag[0][kk], acc[m][0], 0, 0, 0);
            acc[m][1] = __builtin_amdgcn_mfma_f32_16x16x32_f16(a, bfrag[1][kk], acc[m][1], 0, 0, 0);
        }
    }

    const float bcol[2] = { bias[colbase + lrow], bias[colbase + 16 + lrow] };
    #pragma unroll
    for (int m = 0; m < 4; ++m) {
        #pragma unroll
        for (int j = 0; j < 4; ++j) {
            int grow = row0 + m * 16 + lj * 4 + j;
            if (grow >= N) continue;
            float* o = out + (size_t)grow * M + colbase + lrow;
            o[0]  = gelu_exact(acc[m][0][j] + bcol[0]);
            o[16] = gelu_exact(acc[m][1][j] + bcol[1]);
        }
    }
}

// ---------------- CSR build --------------------------------------------------
__global__ __launch_bounds__(256) void count_kernel(
    const int* __restrict__ src, int* __restrict__ cnt, int E)
{
    int e = blockIdx.x * blockDim.x + threadIdx.x;
    if (e < E) atomicAdd(&cnt[src[e]], 1);
}

__global__ __launch_bounds__(256) void scan_blocks(
    const int* __restrict__ cnt, int* __restrict__ offs,
    int* __restrict__ partial, int N)
{
    __shared__ int sh[256];
    const int t = threadIdx.x;
    const int idx = blockIdx.x * 256 + t;
    int v = (idx < N) ? cnt[idx] : 0;
    sh[t] = v;
    __syncthreads();
    #pragma unroll
    for (int off = 1; off < 256; off <<= 1) {
        int x = (t >= off) ? sh[t - off] : 0;
        __syncthreads();
        sh[t] += x;
        __syncthreads();
    }
    if (idx < N) offs[idx] = sh[t] - v;
    if (t == 255) partial[blockIdx.x] = sh[255];
}

__global__ __launch_bounds__(256) void scan_partials(
    int* __restrict__ partial, int nb)
{
    __shared__ int sh[256];
    const int t = threadIdx.x;
    int v = (t < nb) ? partial[t] : 0;
    sh[t] = v;
    __syncthreads();
    #pragma unroll
    for (int off = 1; off < 256; off <<= 1) {
        int x = (t >= off) ? sh[t - off] : 0;
        __syncthreads();
        sh[t] += x;
        __syncthreads();
    }
    if (t < nb) partial[t] = sh[t] - v;
}

__global__ __launch_bounds__(256) void add_offsets(
    int* __restrict__ offs, const int* __restrict__ partial, int N, int E)
{
    const int idx = blockIdx.x * 256 + threadIdx.x;
    if (idx < N) offs[idx] += partial[idx >> 8];
    if (idx == N) offs[N] = E;
}

__global__ __launch_bounds__(256) void fill_csr(
    const int* __restrict__ src, const int* __restrict__ dst,
    const int* __restrict__ offs, int* __restrict__ cursor,
    int* __restrict__ csr_dst, int E)
{
    const int e = blockIdx.x * blockDim.x + threadIdx.x;
    if (e < E) {
        int s = src[e];
        int pos = offs[s] + atomicAdd(&cursor[s], 1);
        csr_dst[pos] = dst[e];
    }
}

// one wave per node: agg[n] = mean over CSR neighbors of y[d]
__global__ __launch_bounds__(256) void aggregate_kernel(
    const float* __restrict__ y,
    const int* __restrict__ csr_dst, const int* __restrict__ offs,
    float* __restrict__ agg, int N)
{
    const int wave = (blockIdx.x * blockDim.x + threadIdx.x) >> 6;
    const int lane = threadIdx.x & 63;
    if (wave >= N) return;
    const int lo = offs[wave];
    const int hi = offs[wave + 1];
    float a0 = 0.0f, a1 = 0.0f;
    for (int base = lo; base < hi; base += 64) {
        int m = hi - base;
        if (m > 64) m = 64;
        int myd = (base + lane < hi) ? csr_dst[base + lane] : 0;
        #pragma unroll 4
        for (int i = 0; i < m; ++i) {
            int d = __shfl(myd, i);
            const float2 v = *reinterpret_cast<const float2*>(
                y + (size_t)d * 128 + lane * 2);
            a0 += v.x;
            a1 += v.y;
        }
    }
    const float inv = (hi > lo) ? 1.0f / (float)(hi - lo) : 0.0f;
    float2 o;
    o.x = a0 * inv;
    o.y = a1 * inv;
    *reinterpret_cast<float2*>(agg + (size_t)wave * 128 + lane * 2) = o;
}

extern "C" void kernel_launch(void* const* d_in, const int* in_sizes, int n_in,
                              void* d_out, int out_size, void* d_ws, size_t ws_size,
                              hipStream_t stream) {
    const float* nf   = (const float*)d_in[0];
    const int*   esrc = (const int*)d_in[1];
    const int*   edst = (const int*)d_in[2];
    const int*   nidx = (const int*)d_in[3];
    auto in = [&](int i) { return (const float*)d_in[i]; };

    const int N = in_sizes[3];       // 50000
    const int E = in_sizes[1];       // 800000
    const int H = 128;

    float* xA  = (float*)d_ws;
    float* xB  = xA + (size_t)N * H;
    float* y   = xB + (size_t)N * H;
    float* agg = y  + (size_t)N * H;

    _Float16* WT0 = (_Float16*)(agg + (size_t)N * H);   // pre   256x128
    _Float16* WT2 = WT0 + 256 * 128;                    // c1u   256x128
    _Float16* WT4 = WT2 + 256 * 128;                    // c2u   256x128
    _Float16* WT1 = WT4 + 256 * 128;                    // c1p   128x128
    _Float16* WT3 = WT1 + 128 * 128;                    // c2p   128x128
    _Float16* WT5 = WT3 + 128 * 128;                    // post  128x128
    float* pb     = (float*)(WT5 + 128 * 128);          // 6 x 128 biases
    int*   cnt     = (int*)(pb + 6 * 128);
    int*   offs    = cnt + N;                 // N+1
    int*   cursor  = offs + (N + 1);
    int*   partial = cursor + N;              // 256
    int*   csr_dst = partial + 256;           // E

    const int ffnGrid = (N + 63) / 64;
    const int nb = (N + 255) / 256;

    // ---- CSR build (reused by both convs) ----
    hipMemsetAsync(cnt, 0, (size_t)N * sizeof(int), stream);
    hipMemsetAsync(cursor, 0, (size_t)N * sizeof(int), stream);
    count_kernel<<<(E + 255) / 256, 256, 0, stream>>>(esrc, cnt, E);
    scan_blocks<<<nb, 256, 0, stream>>>(cnt, offs, partial, N);
    scan_partials<<<1, 256, 0, stream>>>(partial, nb);
    add_offsets<<<(N + 256) / 256, 256, 0, stream>>>(offs, partial, N, E);
    fill_csr<<<(E + 255) / 256, 256, 0, stream>>>(esrc, edst, offs, cursor, csr_dst, E);

    // ---- BN-folded fp16 weights ----
    prep_w<256, 128><<<128, 256, 0, stream>>>(in(4),  in(5),  in(6),  in(7),  in(8),  in(9),  WT0, pb + 0*128);
    prep_w<128, 128><<<128, 256, 0, stream>>>(in(10), in(11), in(12), in(13), in(14), in(15), WT1, pb + 1*128);
    prep_w<256, 128><<<128, 256, 0, stream>>>(in(16), in(17), in(18), in(19), in(20), in(21), WT2, pb + 2*128);
    prep_w<128, 128><<<128, 256, 0, stream>>>(in(22), in(23), in(24), in(25), in(26), in(27), WT3, pb + 3*128);
    prep_w<256, 128><<<128, 256, 0, stream>>>(in(28), in(29), in(30), in(31), in(32), in(33), WT4, pb + 4*128);
    prep_w<128, 128><<<128, 256, 0, stream>>>(in(34), in(35), in(36), in(37), in(38), in(39), WT5, pb + 5*128);

    // ---- pre FFN: [N,256] -> [N,128] ----
    ffn_mfma<256><<<ffnGrid, 256, 0, stream>>>(nf, 256, nullptr, WT0, pb + 0*128, xA, N);

    // ---- conv1 ----
    ffn_mfma<128><<<ffnGrid, 256, 0, stream>>>(xA, 128, nullptr, WT1, pb + 1*128, y, N);
    aggregate_kernel<<<(N * 64 + 255) / 256, 256, 0, stream>>>(y, csr_dst, offs, agg, N);
    ffn_mfma<256><<<ffnGrid, 256, 0, stream>>>(xA, 128, agg, WT2, pb + 2*128, xB, N);

    // ---- conv2 ----
    ffn_mfma<128><<<ffnGrid, 256, 0, stream>>>(xB, 128, nullptr, WT3, pb + 3*128, y, N);
    aggregate_kernel<<<(N * 64 + 255) / 256, 256, 0, stream>>>(y, csr_dst, offs, agg, N);
    ffn_mfma<256><<<ffnGrid, 256, 0, stream>>>(xB, 128, agg, WT4, pb + 4*128, xA, N);

    // ---- post FFN ----
    ffn_mfma<128><<<ffnGrid, 256, 0, stream>>>(xA, 128, nullptr, WT5, pb + 5*128, xB, N);

    // ---- final linear with node_idx gather ----
    ffn_kernel<128, 32, false, false><<<ffnGrid, 256, 0, stream>>>(
        xB, 128, nullptr, nidx,
        nullptr, nullptr, nullptr, nullptr, in(40), in(41), (float*)d_out, N);
}

// Round 4
// 337.968 us; speedup vs baseline: 5.5484x; 1.1578x over previous
//
#include <hip/hip_runtime.h>
#include <math.h>

#define BN_EPS 1e-5f

typedef _Float16 f16x8 __attribute__((ext_vector_type(8)));
typedef _Float16 f16x2 __attribute__((ext_vector_type(2)));
typedef float f32x4 __attribute__((ext_vector_type(4)));

__device__ __forceinline__ float gelu_exact(float x) {
    return 0.5f * x * (1.0f + erff(x * 0.7071067811865475f));
}

// ---------------- BN-fold weight prep: WT[j][k] = rs*g*W[k][j] (fp16),
// bias_out[j] = bias[j] + sum_k (b[k]-m[k]*rs*g)*W[k][j] -------------------
template<int K, int M>
__global__ __launch_bounds__(256) void prep_w(
    const float* __restrict__ gg, const float* __restrict__ bb,
    const float* __restrict__ mm, const float* __restrict__ vv,
    const float* __restrict__ W, const float* __restrict__ bias,
    _Float16* __restrict__ WT, float* __restrict__ bias_out)
{
    const int j = blockIdx.x;
    const int t = threadIdx.x;
    __shared__ float red[256];
    float acc = 0.0f;
    for (int k = t; k < K; k += 256) {
        float rs = rsqrtf(vv[k] + BN_EPS) * gg[k];
        float w  = W[(size_t)k * M + j];
        WT[(size_t)j * K + k] = (_Float16)(rs * w);
        acc += (bb[k] - mm[k] * rs) * w;
    }
    red[t] = acc;
    __syncthreads();
    #pragma unroll
    for (int s = 128; s > 0; s >>= 1) {
        if (t < s) red[t] += red[t + s];
        __syncthreads();
    }
    if (t == 0) bias_out[j] = bias[j] + red[0];
}

// ---------------- MFMA FFN: out[64 x 128] per block, fp16 out ---------------
// TIn = float (first layer) or _Float16. x staged in LDS fp16, XOR-swizzled.
template<int K, typename TIn>
__global__ __launch_bounds__(256) void ffn_mfma(
    const TIn* __restrict__ x1, int K1,
    const TIn* __restrict__ x2,
    const _Float16* __restrict__ WT,
    const float* __restrict__ bias,
    _Float16* __restrict__ out, int N)
{
    constexpr int M  = 128;
    constexpr int KB = K * 2;          // row bytes in LDS
    constexpr int CPR = K / 8;         // 8-elem chunks per row
    constexpr int NKK = K / 32;        // K-steps
    __shared__ __align__(16) char xs[64 * KB];

    const int tid  = threadIdx.x;
    const int row0 = blockIdx.x * 64;

    // stage 64 x K -> fp16, swizzled
    for (int c = tid; c < 64 * CPR; c += 256) {
        int r  = c / CPR;
        int kc = c % CPR;
        int k0 = kc * 8;
        int row = row0 + r;
        f16x8 h;
        #pragma unroll
        for (int i = 0; i < 8; ++i) h[i] = (_Float16)0.0f;
        if (row < N) {
            const TIn* src; int kk, stride;
            if (k0 < K1) { src = x1; kk = k0;      stride = K1; }
            else         { src = x2; kk = k0 - K1; stride = K - K1; }
            const TIn* p = src + (size_t)row * stride + kk;
            if constexpr (sizeof(TIn) == 2) {
                h = *reinterpret_cast<const f16x8*>(p);
            } else {
                const float4 a = *reinterpret_cast<const float4*>(p);
                const float4 b = *reinterpret_cast<const float4*>(p + 4);
                h[0]=(_Float16)a.x; h[1]=(_Float16)a.y; h[2]=(_Float16)a.z; h[3]=(_Float16)a.w;
                h[4]=(_Float16)b.x; h[5]=(_Float16)b.y; h[6]=(_Float16)b.z; h[7]=(_Float16)b.w;
            }
        }
        int byte = r * KB + ((k0 * 2) ^ ((r & 7) << 4));
        *reinterpret_cast<f16x8*>(&xs[byte]) = h;
    }
    __syncthreads();

    const int wave = tid >> 6;
    const int lane = tid & 63;
    const int lrow = lane & 15;
    const int lj   = lane >> 4;
    const int lk   = lj * 8;
    const int colbase = wave * 32;

    // preload B fragments (W' cols), 16B each, L2-resident
    f16x8 bfrag[2][NKK];
    #pragma unroll
    for (int n = 0; n < 2; ++n) {
        int col = colbase + n * 16 + lrow;
        #pragma unroll
        for (int kk = 0; kk < NKK; ++kk)
            bfrag[n][kk] = *reinterpret_cast<const f16x8*>(
                WT + (size_t)col * K + kk * 32 + lk);
    }

    f32x4 acc[4][2];
    #pragma unroll
    for (int m = 0; m < 4; ++m)
        #pragma unroll
        for (int n = 0; n < 2; ++n)
            acc[m][n] = (f32x4){0.f, 0.f, 0.f, 0.f};

    #pragma unroll
    for (int kk = 0; kk < NKK; ++kk) {
        #pragma unroll
        for (int m = 0; m < 4; ++m) {
            int r  = m * 16 + lrow;
            int k0 = kk * 32 + lk;
            f16x8 a = *reinterpret_cast<const f16x8*>(
                &xs[r * KB + ((k0 * 2) ^ ((r & 7) << 4))]);
            acc[m][0] = __builtin_amdgcn_mfma_f32_16x16x32_f16(a, bfrag[0][kk], acc[m][0], 0, 0, 0);
            acc[m][1] = __builtin_amdgcn_mfma_f32_16x16x32_f16(a, bfrag[1][kk], acc[m][1], 0, 0, 0);
        }
    }

    const float bcol[2] = { bias[colbase + lrow], bias[colbase + 16 + lrow] };
    #pragma unroll
    for (int m = 0; m < 4; ++m) {
        #pragma unroll
        for (int j = 0; j < 4; ++j) {
            int grow = row0 + m * 16 + lj * 4 + j;
            if (grow >= N) continue;
            _Float16* o = out + (size_t)grow * M + colbase + lrow;
            o[0]  = (_Float16)gelu_exact(acc[m][0][j] + bcol[0]);
            o[16] = (_Float16)gelu_exact(acc[m][1][j] + bcol[1]);
        }
    }
}

// ---------------- final linear: out[n] = x[gidx[n]] @ W + b  (fp16 in, f32 out)
__global__ __launch_bounds__(256) void final_linear(
    const _Float16* __restrict__ x, const int* __restrict__ gidx,
    const float* __restrict__ W, const float* __restrict__ bias,
    float* __restrict__ out, int N)
{
    __shared__ float xs[64 * 128];
    const int tid = threadIdx.x;
    const int row0 = blockIdx.x * 64;

    for (int c = tid; c < 64 * 16; c += 256) {
        int r  = c >> 4;
        int k0 = (c & 15) * 8;
        int row = row0 + r;
        float v[8];
        #pragma unroll
        for (int i = 0; i < 8; ++i) v[i] = 0.0f;
        if (row < N) {
            int rs = gidx ? gidx[row] : row;
            f16x8 h = *reinterpret_cast<const f16x8*>(x + (size_t)rs * 128 + k0);
            #pragma unroll
            for (int i = 0; i < 8; ++i) v[i] = (float)h[i];
        }
        #pragma unroll
        for (int i = 0; i < 8; ++i) xs[r * 128 + k0 + i] = v[i];
    }
    __syncthreads();

    // M=32: 8 col-groups of 4; RPT = 64*8/256 = 2 rows/thread
    const int cg = tid & 7;
    const int rg = tid >> 3;
    const int j0 = cg * 4;
    const int r0 = rg * 2;

    float acc[2][4];
    acc[0][0]=0; acc[0][1]=0; acc[0][2]=0; acc[0][3]=0;
    acc[1][0]=0; acc[1][1]=0; acc[1][2]=0; acc[1][3]=0;

    #pragma unroll 4
    for (int k = 0; k < 128; ++k) {
        const float4 w = *reinterpret_cast<const float4*>(W + (size_t)k * 32 + j0);
        #pragma unroll
        for (int r = 0; r < 2; ++r) {
            float xv = xs[(r0 + r) * 128 + k];
            acc[r][0] = fmaf(xv, w.x, acc[r][0]);
            acc[r][1] = fmaf(xv, w.y, acc[r][1]);
            acc[r][2] = fmaf(xv, w.z, acc[r][2]);
            acc[r][3] = fmaf(xv, w.w, acc[r][3]);
        }
    }

    #pragma unroll
    for (int r = 0; r < 2; ++r) {
        int row = row0 + r0 + r;
        if (row >= N) continue;
        float4 o;
        o.x = acc[r][0] + bias[j0 + 0];
        o.y = acc[r][1] + bias[j0 + 1];
        o.z = acc[r][2] + bias[j0 + 2];
        o.w = acc[r][3] + bias[j0 + 3];
        *reinterpret_cast<float4*>(out + (size_t)row * 32 + j0) = o;
    }
}

// ---------------- CSR build --------------------------------------------------
__global__ __launch_bounds__(256) void count_kernel(
    const int* __restrict__ src, int* __restrict__ cnt, int E)
{
    int e = blockIdx.x * blockDim.x + threadIdx.x;
    if (e < E) atomicAdd(&cnt[src[e]], 1);
}

__global__ __launch_bounds__(256) void scan_blocks(
    const int* __restrict__ cnt, int* __restrict__ offs,
    int* __restrict__ partial, int N)
{
    __shared__ int sh[256];
    const int t = threadIdx.x;
    const int idx = blockIdx.x * 256 + t;
    int v = (idx < N) ? cnt[idx] : 0;
    sh[t] = v;
    __syncthreads();
    #pragma unroll
    for (int off = 1; off < 256; off <<= 1) {
        int x = (t >= off) ? sh[t - off] : 0;
        __syncthreads();
        sh[t] += x;
        __syncthreads();
    }
    if (idx < N) offs[idx] = sh[t] - v;
    if (t == 255) partial[blockIdx.x] = sh[255];
}

__global__ __launch_bounds__(256) void scan_partials(
    int* __restrict__ partial, int nb)
{
    __shared__ int sh[256];
    const int t = threadIdx.x;
    int v = (t < nb) ? partial[t] : 0;
    sh[t] = v;
    __syncthreads();
    #pragma unroll
    for (int off = 1; off < 256; off <<= 1) {
        int x = (t >= off) ? sh[t - off] : 0;
        __syncthreads();
        sh[t] += x;
        __syncthreads();
    }
    if (t < nb) partial[t] = sh[t] - v;
}

__global__ __launch_bounds__(256) void add_offsets(
    int* __restrict__ offs, const int* __restrict__ partial, int N, int E)
{
    const int idx = blockIdx.x * 256 + threadIdx.x;
    if (idx < N) offs[idx] += partial[idx >> 8];
    if (idx == N) offs[N] = E;
}

__global__ __launch_bounds__(256) void fill_csr(
    const int* __restrict__ src, const int* __restrict__ dst,
    const int* __restrict__ offs, int* __restrict__ cursor,
    int* __restrict__ csr_dst, int E)
{
    const int e = blockIdx.x * blockDim.x + threadIdx.x;
    if (e < E) {
        int s = src[e];
        int pos = offs[s] + atomicAdd(&cursor[s], 1);
        csr_dst[pos] = dst[e];
    }
}

// one wave per node: agg[n] = mean over CSR neighbors of y[d]  (fp16 y/agg)
__global__ __launch_bounds__(256) void aggregate_kernel(
    const _Float16* __restrict__ y,
    const int* __restrict__ csr_dst, const int* __restrict__ offs,
    _Float16* __restrict__ agg, int N)
{
    const int wave = (blockIdx.x * blockDim.x + threadIdx.x) >> 6;
    const int lane = threadIdx.x & 63;
    if (wave >= N) return;
    const int lo = offs[wave];
    const int hi = offs[wave + 1];
    float a0 = 0.0f, a1 = 0.0f;
    for (int base = lo; base < hi; base += 64) {
        int m = hi - base;
        if (m > 64) m = 64;
        int myd = (base + lane < hi) ? csr_dst[base + lane] : 0;
        #pragma unroll 4
        for (int i = 0; i < m; ++i) {
            int d = __shfl(myd, i);
            const f16x2 v = *reinterpret_cast<const f16x2*>(
                y + (size_t)d * 128 + lane * 2);
            a0 += (float)v[0];
            a1 += (float)v[1];
        }
    }
    const float inv = (hi > lo) ? 1.0f / (float)(hi - lo) : 0.0f;
    f16x2 o;
    o[0] = (_Float16)(a0 * inv);
    o[1] = (_Float16)(a1 * inv);
    *reinterpret_cast<f16x2*>(agg + (size_t)wave * 128 + lane * 2) = o;
}

extern "C" void kernel_launch(void* const* d_in, const int* in_sizes, int n_in,
                              void* d_out, int out_size, void* d_ws, size_t ws_size,
                              hipStream_t stream) {
    const float* nf   = (const float*)d_in[0];
    const int*   esrc = (const int*)d_in[1];
    const int*   edst = (const int*)d_in[2];
    const int*   nidx = (const int*)d_in[3];
    auto in = [&](int i) { return (const float*)d_in[i]; };

    const int N = in_sizes[3];       // 50000
    const int E = in_sizes[1];       // 800000
    const int H = 128;

    _Float16* xA  = (_Float16*)d_ws;
    _Float16* xB  = xA + (size_t)N * H;
    _Float16* y   = xB + (size_t)N * H;
    _Float16* agg = y  + (size_t)N * H;

    _Float16* WT0 = agg + (size_t)N * H;                // pre   256x128
    _Float16* WT2 = WT0 + 256 * 128;                    // c1u   256x128
    _Float16* WT4 = WT2 + 256 * 128;                    // c2u   256x128
    _Float16* WT1 = WT4 + 256 * 128;                    // c1p   128x128
    _Float16* WT3 = WT1 + 128 * 128;                    // c2p   128x128
    _Float16* WT5 = WT3 + 128 * 128;                    // post  128x128
    float* pb     = (float*)(WT5 + 128 * 128);          // 6 x 128 biases
    int*   cnt     = (int*)(pb + 6 * 128);
    int*   cursor  = cnt + N;
    int*   offs    = cursor + N;              // N+1
    int*   partial = offs + (N + 1);          // 256
    int*   csr_dst = partial + 256;           // E

    const int ffnGrid = (N + 63) / 64;
    const int nb = (N + 255) / 256;

    // ---- CSR build (reused by both convs) ----
    hipMemsetAsync(cnt, 0, (size_t)(2 * N) * sizeof(int), stream);
    count_kernel<<<(E + 255) / 256, 256, 0, stream>>>(esrc, cnt, E);
    scan_blocks<<<nb, 256, 0, stream>>>(cnt, offs, partial, N);
    scan_partials<<<1, 256, 0, stream>>>(partial, nb);
    add_offsets<<<(N + 256) / 256, 256, 0, stream>>>(offs, partial, N, E);
    fill_csr<<<(E + 255) / 256, 256, 0, stream>>>(esrc, edst, offs, cursor, csr_dst, E);

    // ---- BN-folded fp16 weights ----
    prep_w<256, 128><<<128, 256, 0, stream>>>(in(4),  in(5),  in(6),  in(7),  in(8),  in(9),  WT0, pb + 0*128);
    prep_w<128, 128><<<128, 256, 0, stream>>>(in(10), in(11), in(12), in(13), in(14), in(15), WT1, pb + 1*128);
    prep_w<256, 128><<<128, 256, 0, stream>>>(in(16), in(17), in(18), in(19), in(20), in(21), WT2, pb + 2*128);
    prep_w<128, 128><<<128, 256, 0, stream>>>(in(22), in(23), in(24), in(25), in(26), in(27), WT3, pb + 3*128);
    prep_w<256, 128><<<128, 256, 0, stream>>>(in(28), in(29), in(30), in(31), in(32), in(33), WT4, pb + 4*128);
    prep_w<128, 128><<<128, 256, 0, stream>>>(in(34), in(35), in(36), in(37), in(38), in(39), WT5, pb + 5*128);

    // ---- pre FFN: [N,256] f32 -> [N,128] f16 ----
    ffn_mfma<256, float><<<ffnGrid, 256, 0, stream>>>(nf, 256, nullptr, WT0, pb + 0*128, xA, N);

    // ---- conv1 ----
    ffn_mfma<128, _Float16><<<ffnGrid, 256, 0, stream>>>(xA, 128, nullptr, WT1, pb + 1*128, y, N);
    aggregate_kernel<<<(N * 64 + 255) / 256, 256, 0, stream>>>(y, csr_dst, offs, agg, N);
    ffn_mfma<256, _Float16><<<ffnGrid, 256, 0, stream>>>(xA, 128, agg, WT2, pb + 2*128, xB, N);

    // ---- conv2 ----
    ffn_mfma<128, _Float16><<<ffnGrid, 256, 0, stream>>>(xB, 128, nullptr, WT3, pb + 3*128, y, N);
    aggregate_kernel<<<(N * 64 + 255) / 256, 256, 0, stream>>>(y, csr_dst, offs, agg, N);
    ffn_mfma<256, _Float16><<<ffnGrid, 256, 0, stream>>>(xB, 128, agg, WT4, pb + 4*128, xA, N);

    // ---- post FFN ----
    ffn_mfma<128, _Float16><<<ffnGrid, 256, 0, stream>>>(xA, 128, nullptr, WT5, pb + 5*128, xB, N);

    // ---- final linear with node_idx gather ----
    final_linear<<<ffnGrid, 256, 0, stream>>>(xB, nidx, in(40), in(41), (float*)d_out, N);
}

// Round 5
// 284.658 us; speedup vs baseline: 6.5875x; 1.1873x over previous
//
#include <hip/hip_runtime.h>
#include <math.h>

#define BN_EPS 1e-5f

typedef _Float16 f16x8 __attribute__((ext_vector_type(8)));
typedef _Float16 f16x2 __attribute__((ext_vector_type(2)));
typedef float f32x4 __attribute__((ext_vector_type(4)));

__device__ __forceinline__ float gelu_exact(float x) {
    return 0.5f * x * (1.0f + erff(x * 0.7071067811865475f));
}

// ---------------- BN-fold weight prep: WT[j][k] = rs*g*W[k][j] (fp16),
// bias_out[j] = bias[j] + sum_k (b[k]-m[k]*rs*g)*W[k][j] -------------------
template<int K, int M>
__global__ __launch_bounds__(256) void prep_w(
    const float* __restrict__ gg, const float* __restrict__ bb,
    const float* __restrict__ mm, const float* __restrict__ vv,
    const float* __restrict__ W, const float* __restrict__ bias,
    _Float16* __restrict__ WT, float* __restrict__ bias_out)
{
    const int j = blockIdx.x;
    const int t = threadIdx.x;
    __shared__ float red[256];
    float acc = 0.0f;
    for (int k = t; k < K; k += 256) {
        float rs = rsqrtf(vv[k] + BN_EPS) * gg[k];
        float w  = W[(size_t)k * M + j];
        WT[(size_t)j * K + k] = (_Float16)(rs * w);
        acc += (bb[k] - mm[k] * rs) * w;
    }
    red[t] = acc;
    __syncthreads();
    #pragma unroll
    for (int s = 128; s > 0; s >>= 1) {
        if (t < s) red[t] += red[t + s];
        __syncthreads();
    }
    if (t == 0) bias_out[j] = bias[j] + red[0];
}

// ---------------- MFMA FFN: out[64 x 128] per block, fp16 out ---------------
// TIn = float (first layer) or _Float16. x staged in LDS fp16, XOR-swizzled.
template<int K, typename TIn>
__global__ __launch_bounds__(256) void ffn_mfma(
    const TIn* __restrict__ x1, int K1,
    const TIn* __restrict__ x2,
    const _Float16* __restrict__ WT,
    const float* __restrict__ bias,
    _Float16* __restrict__ out, int N)
{
    constexpr int M  = 128;
    constexpr int KB = K * 2;          // row bytes in LDS
    constexpr int CPR = K / 8;         // 8-elem chunks per row
    constexpr int NKK = K / 32;        // K-steps
    __shared__ __align__(16) char xs[64 * KB];

    const int tid  = threadIdx.x;
    const int row0 = blockIdx.x * 64;

    // stage 64 x K -> fp16, swizzled
    for (int c = tid; c < 64 * CPR; c += 256) {
        int r  = c / CPR;
        int kc = c % CPR;
        int k0 = kc * 8;
        int row = row0 + r;
        f16x8 h;
        #pragma unroll
        for (int i = 0; i < 8; ++i) h[i] = (_Float16)0.0f;
        if (row < N) {
            const TIn* src; int kk, stride;
            if (k0 < K1) { src = x1; kk = k0;      stride = K1; }
            else         { src = x2; kk = k0 - K1; stride = K - K1; }
            const TIn* p = src + (size_t)row * stride + kk;
            if constexpr (sizeof(TIn) == 2) {
                h = *reinterpret_cast<const f16x8*>(p);
            } else {
                const float4 a = *reinterpret_cast<const float4*>(p);
                const float4 b = *reinterpret_cast<const float4*>(p + 4);
                h[0]=(_Float16)a.x; h[1]=(_Float16)a.y; h[2]=(_Float16)a.z; h[3]=(_Float16)a.w;
                h[4]=(_Float16)b.x; h[5]=(_Float16)b.y; h[6]=(_Float16)b.z; h[7]=(_Float16)b.w;
            }
        }
        int byte = r * KB + ((k0 * 2) ^ ((r & 7) << 4));
        *reinterpret_cast<f16x8*>(&xs[byte]) = h;
    }
    __syncthreads();

    const int wave = tid >> 6;
    const int lane = tid & 63;
    const int lrow = lane & 15;
    const int lj   = lane >> 4;
    const int lk   = lj * 8;
    const int colbase = wave * 32;

    // preload B fragments (W' cols), 16B each, L2-resident
    f16x8 bfrag[2][NKK];
    #pragma unroll
    for (int n = 0; n < 2; ++n) {
        int col = colbase + n * 16 + lrow;
        #pragma unroll
        for (int kk = 0; kk < NKK; ++kk)
            bfrag[n][kk] = *reinterpret_cast<const f16x8*>(
                WT + (size_t)col * K + kk * 32 + lk);
    }

    f32x4 acc[4][2];
    #pragma unroll
    for (int m = 0; m < 4; ++m)
        #pragma unroll
        for (int n = 0; n < 2; ++n)
            acc[m][n] = (f32x4){0.f, 0.f, 0.f, 0.f};

    #pragma unroll
    for (int kk = 0; kk < NKK; ++kk) {
        #pragma unroll
        for (int m = 0; m < 4; ++m) {
            int r  = m * 16 + lrow;
            int k0 = kk * 32 + lk;
            f16x8 a = *reinterpret_cast<const f16x8*>(
                &xs[r * KB + ((k0 * 2) ^ ((r & 7) << 4))]);
            acc[m][0] = __builtin_amdgcn_mfma_f32_16x16x32_f16(a, bfrag[0][kk], acc[m][0], 0, 0, 0);
            acc[m][1] = __builtin_amdgcn_mfma_f32_16x16x32_f16(a, bfrag[1][kk], acc[m][1], 0, 0, 0);
        }
    }

    const float bcol[2] = { bias[colbase + lrow], bias[colbase + 16 + lrow] };
    #pragma unroll
    for (int m = 0; m < 4; ++m) {
        #pragma unroll
        for (int j = 0; j < 4; ++j) {
            int grow = row0 + m * 16 + lj * 4 + j;
            if (grow >= N) continue;
            _Float16* o = out + (size_t)grow * M + colbase + lrow;
            o[0]  = (_Float16)gelu_exact(acc[m][0][j] + bcol[0]);
            o[16] = (_Float16)gelu_exact(acc[m][1][j] + bcol[1]);
        }
    }
}

// ---------------- final linear: out[n] = x[gidx[n]] @ W + b  (fp16 in, f32 out)
__global__ __launch_bounds__(256) void final_linear(
    const _Float16* __restrict__ x, const int* __restrict__ gidx,
    const float* __restrict__ W, const float* __restrict__ bias,
    float* __restrict__ out, int N)
{
    __shared__ float xs[64 * 128];
    const int tid = threadIdx.x;
    const int row0 = blockIdx.x * 64;

    for (int c = tid; c < 64 * 16; c += 256) {
        int r  = c >> 4;
        int k0 = (c & 15) * 8;
        int row = row0 + r;
        float v[8];
        #pragma unroll
        for (int i = 0; i < 8; ++i) v[i] = 0.0f;
        if (row < N) {
            int rs = gidx ? gidx[row] : row;
            f16x8 h = *reinterpret_cast<const f16x8*>(x + (size_t)rs * 128 + k0);
            #pragma unroll
            for (int i = 0; i < 8; ++i) v[i] = (float)h[i];
        }
        #pragma unroll
        for (int i = 0; i < 8; ++i) xs[r * 128 + k0 + i] = v[i];
    }
    __syncthreads();

    // M=32: 8 col-groups of 4; RPT = 64*8/256 = 2 rows/thread
    const int cg = tid & 7;
    const int rg = tid >> 3;
    const int j0 = cg * 4;
    const int r0 = rg * 2;

    float acc[2][4];
    acc[0][0]=0; acc[0][1]=0; acc[0][2]=0; acc[0][3]=0;
    acc[1][0]=0; acc[1][1]=0; acc[1][2]=0; acc[1][3]=0;

    #pragma unroll 4
    for (int k = 0; k < 128; ++k) {
        const float4 w = *reinterpret_cast<const float4*>(W + (size_t)k * 32 + j0);
        #pragma unroll
        for (int r = 0; r < 2; ++r) {
            float xv = xs[(r0 + r) * 128 + k];
            acc[r][0] = fmaf(xv, w.x, acc[r][0]);
            acc[r][1] = fmaf(xv, w.y, acc[r][1]);
            acc[r][2] = fmaf(xv, w.z, acc[r][2]);
            acc[r][3] = fmaf(xv, w.w, acc[r][3]);
        }
    }

    #pragma unroll
    for (int r = 0; r < 2; ++r) {
        int row = row0 + r0 + r;
        if (row >= N) continue;
        float4 o;
        o.x = acc[r][0] + bias[j0 + 0];
        o.y = acc[r][1] + bias[j0 + 1];
        o.z = acc[r][2] + bias[j0 + 2];
        o.w = acc[r][3] + bias[j0 + 3];
        *reinterpret_cast<float4*>(out + (size_t)row * 32 + j0) = o;
    }
}

// ---------------- CSR build --------------------------------------------------
__global__ __launch_bounds__(256) void count_kernel(
    const int* __restrict__ src, int* __restrict__ cnt, int E)
{
    int e = blockIdx.x * blockDim.x + threadIdx.x;
    if (e < E) atomicAdd(&cnt[src[e]], 1);
}

__global__ __launch_bounds__(256) void scan_blocks(
    const int* __restrict__ cnt, int* __restrict__ offs,
    int* __restrict__ partial, int N)
{
    __shared__ int sh[256];
    const int t = threadIdx.x;
    const int idx = blockIdx.x * 256 + t;
    int v = (idx < N) ? cnt[idx] : 0;
    sh[t] = v;
    __syncthreads();
    #pragma unroll
    for (int off = 1; off < 256; off <<= 1) {
        int x = (t >= off) ? sh[t - off] : 0;
        __syncthreads();
        sh[t] += x;
        __syncthreads();
    }
    if (idx < N) offs[idx] = sh[t] - v;
    if (t == 255) partial[blockIdx.x] = sh[255];
}

__global__ __launch_bounds__(256) void scan_partials(
    int* __restrict__ partial, int nb)
{
    __shared__ int sh[256];
    const int t = threadIdx.x;
    int v = (t < nb) ? partial[t] : 0;
    sh[t] = v;
    __syncthreads();
    #pragma unroll
    for (int off = 1; off < 256; off <<= 1) {
        int x = (t >= off) ? sh[t - off] : 0;
        __syncthreads();
        sh[t] += x;
        __syncthreads();
    }
    if (t < nb) partial[t] = sh[t] - v;
}

__global__ __launch_bounds__(256) void add_offsets(
    int* __restrict__ offs, const int* __restrict__ partial, int N, int E)
{
    const int idx = blockIdx.x * 256 + threadIdx.x;
    if (idx < N) offs[idx] += partial[idx >> 8];
    if (idx == N) offs[N] = E;
}

__global__ __launch_bounds__(256) void fill_csr(
    const int* __restrict__ src, const int* __restrict__ dst,
    const int* __restrict__ offs, int* __restrict__ cursor,
    int* __restrict__ csr_dst, int E)
{
    const int e = blockIdx.x * blockDim.x + threadIdx.x;
    if (e < E) {
        int s = src[e];
        int pos = offs[s] + atomicAdd(&cursor[s], 1);
        csr_dst[pos] = dst[e];
    }
}

// one wave per node, 4 neighbors per load step (16 lanes x 16B each = 1 row).
// agg[n] = mean over CSR neighbors of y[d]  (fp16 y/agg, fp32 accum)
__global__ __launch_bounds__(256) void aggregate_kernel(
    const _Float16* __restrict__ y,
    const int* __restrict__ csr_dst, const int* __restrict__ offs,
    _Float16* __restrict__ agg, int N)
{
    const int wave = (blockIdx.x * blockDim.x + threadIdx.x) >> 6;
    const int lane = threadIdx.x & 63;
    if (wave >= N) return;
    const int lo = offs[wave];
    const int hi = offs[wave + 1];
    const int sub = lane >> 4;          // neighbor slot 0..3
    const int col = (lane & 15) * 8;    // 8 fp16 = 16 B per lane

    float a[8];
    #pragma unroll
    for (int j = 0; j < 8; ++j) a[j] = 0.0f;

    for (int base = lo; base < hi; base += 64) {
        int myd = (base + lane < hi) ? csr_dst[base + lane] : -1;
        int m = hi - base;
        if (m > 64) m = 64;
        int ng = (m + 3) >> 2;          // groups of 4 neighbors
        #pragma unroll 4
        for (int i = 0; i < ng; ++i) {
            int d = __shfl(myd, i * 4 + sub);
            if (d >= 0) {
                f16x8 v = *reinterpret_cast<const f16x8*>(
                    y + (size_t)d * 128 + col);
                #pragma unroll
                for (int j = 0; j < 8; ++j) a[j] += (float)v[j];
            }
        }
    }

    // reduce across the 4 neighbor slots (lane bits 4 and 5)
    #pragma unroll
    for (int j = 0; j < 8; ++j) {
        a[j] += __shfl_xor(a[j], 16);
        a[j] += __shfl_xor(a[j], 32);
    }

    if (lane < 16) {
        const float inv = (hi > lo) ? 1.0f / (float)(hi - lo) : 0.0f;
        f16x8 o;
        #pragma unroll
        for (int j = 0; j < 8; ++j) o[j] = (_Float16)(a[j] * inv);
        *reinterpret_cast<f16x8*>(agg + (size_t)wave * 128 + col) = o;
    }
}

extern "C" void kernel_launch(void* const* d_in, const int* in_sizes, int n_in,
                              void* d_out, int out_size, void* d_ws, size_t ws_size,
                              hipStream_t stream) {
    const float* nf   = (const float*)d_in[0];
    const int*   esrc = (const int*)d_in[1];
    const int*   edst = (const int*)d_in[2];
    const int*   nidx = (const int*)d_in[3];
    auto in = [&](int i) { return (const float*)d_in[i]; };

    const int N = in_sizes[3];       // 50000
    const int E = in_sizes[1];       // 800000
    const int H = 128;

    _Float16* xA  = (_Float16*)d_ws;
    _Float16* xB  = xA + (size_t)N * H;
    _Float16* y   = xB + (size_t)N * H;
    _Float16* agg = y  + (size_t)N * H;

    _Float16* WT0 = agg + (size_t)N * H;                // pre   256x128
    _Float16* WT2 = WT0 + 256 * 128;                    // c1u   256x128
    _Float16* WT4 = WT2 + 256 * 128;                    // c2u   256x128
    _Float16* WT1 = WT4 + 256 * 128;                    // c1p   128x128
    _Float16* WT3 = WT1 + 128 * 128;                    // c2p   128x128
    _Float16* WT5 = WT3 + 128 * 128;                    // post  128x128
    float* pb     = (float*)(WT5 + 128 * 128);          // 6 x 128 biases
    int*   cnt     = (int*)(pb + 6 * 128);
    int*   cursor  = cnt + N;
    int*   offs    = cursor + N;              // N+1
    int*   partial = offs + (N + 1);          // 256
    int*   csr_dst = partial + 256;           // E

    const int ffnGrid = (N + 63) / 64;
    const int nb = (N + 255) / 256;

    // ---- CSR build (reused by both convs) ----
    hipMemsetAsync(cnt, 0, (size_t)(2 * N) * sizeof(int), stream);
    count_kernel<<<(E + 255) / 256, 256, 0, stream>>>(esrc, cnt, E);
    scan_blocks<<<nb, 256, 0, stream>>>(cnt, offs, partial, N);
    scan_partials<<<1, 256, 0, stream>>>(partial, nb);
    add_offsets<<<(N + 256) / 256, 256, 0, stream>>>(offs, partial, N, E);
    fill_csr<<<(E + 255) / 256, 256, 0, stream>>>(esrc, edst, offs, cursor, csr_dst, E);

    // ---- BN-folded fp16 weights ----
    prep_w<256, 128><<<128, 256, 0, stream>>>(in(4),  in(5),  in(6),  in(7),  in(8),  in(9),  WT0, pb + 0*128);
    prep_w<128, 128><<<128, 256, 0, stream>>>(in(10), in(11), in(12), in(13), in(14), in(15), WT1, pb + 1*128);
    prep_w<256, 128><<<128, 256, 0, stream>>>(in(16), in(17), in(18), in(19), in(20), in(21), WT2, pb + 2*128);
    prep_w<128, 128><<<128, 256, 0, stream>>>(in(22), in(23), in(24), in(25), in(26), in(27), WT3, pb + 3*128);
    prep_w<256, 128><<<128, 256, 0, stream>>>(in(28), in(29), in(30), in(31), in(32), in(33), WT4, pb + 4*128);
    prep_w<128, 128><<<128, 256, 0, stream>>>(in(34), in(35), in(36), in(37), in(38), in(39), WT5, pb + 5*128);

    // ---- pre FFN: [N,256] f32 -> [N,128] f16 ----
    ffn_mfma<256, float><<<ffnGrid, 256, 0, stream>>>(nf, 256, nullptr, WT0, pb + 0*128, xA, N);

    // ---- conv1 ----
    ffn_mfma<128, _Float16><<<ffnGrid, 256, 0, stream>>>(xA, 128, nullptr, WT1, pb + 1*128, y, N);
    aggregate_kernel<<<(N * 64 + 255) / 256, 256, 0, stream>>>(y, csr_dst, offs, agg, N);
    ffn_mfma<256, _Float16><<<ffnGrid, 256, 0, stream>>>(xA, 128, agg, WT2, pb + 2*128, xB, N);

    // ---- conv2 ----
    ffn_mfma<128, _Float16><<<ffnGrid, 256, 0, stream>>>(xB, 128, nullptr, WT3, pb + 3*128, y, N);
    aggregate_kernel<<<(N * 64 + 255) / 256, 256, 0, stream>>>(y, csr_dst, offs, agg, N);
    ffn_mfma<256, _Float16><<<ffnGrid, 256, 0, stream>>>(xB, 128, agg, WT4, pb + 4*128, xA, N);

    // ---- post FFN ----
    ffn_mfma<128, _Float16><<<ffnGrid, 256, 0, stream>>>(xA, 128, nullptr, WT5, pb + 5*128, xB, N);

    // ---- final linear with node_idx gather ----
    final_linear<<<ffnGrid, 256, 0, stream>>>(xB, nidx, in(40), in(41), (float*)d_out, N);
}